// Round 4
// baseline (269.362 us; speedup 1.0000x reference)
//
#include <hip/hip_runtime.h>

// Depthwise 3x3 conv (diagonal-masked dense conv), fp32.
// x: (S*B=32, C=256, H=64, W=64)  W: (256,256,3,3) -> only diag [c,c,:,:] used.
//
// Direct-from-global version: NO LDS, NO barriers, NO shuffles.
// Rationale (round-3 post-mortem): the LDS-staged kernel's limiter was not
// bank conflicts (stride-65 pad was a null result) but phase serialization —
// load / vmcnt-drain / barrier / compute phases empty the VMEM queue in
// lockstep across resident blocks, capping effective HBM BW at ~3.7 TB/s.
// Here every thread reads its 3x6 input window straight from global memory:
// per output row, 1 aligned float4 + 2 guarded scalar loads. The 3x re-read
// + halo overlap is served by L1/L2 (plane is block-local, 16 KiB vs 32 KiB
// L1); HBM still sees each input byte once. 36 independent loads per thread,
// no sync anywhere -> VMEM queue stays full, pure HBM stream.
// Output is write-once -> nontemporal stores.

#define C_CH 256
#define H_SP 64
#define W_SP 64
#define PLANE (H_SP * W_SP) // 4096 floats

typedef float f32x4 __attribute__((ext_vector_type(4)));

__global__ __launch_bounds__(256) void dwconv3x3_direct(
    const float* __restrict__ x,
    const float* __restrict__ Wfull,
    float* __restrict__ out)
{
    const int p = blockIdx.x;            // plane index in [0, 8192)
    const int c = p & (C_CH - 1);        // channel (inner dim of leading index)
    const float* __restrict__ xp = x + (size_t)p * PLANE;
    float* __restrict__ op = out + (size_t)p * PLANE;

    // 9 diagonal weights, block-uniform: W[((c*C + c)*3 + kh)*3 + kw]
    const float* __restrict__ wp = Wfull + (size_t)c * (C_CH + 1) * 9;
    const float w00 = wp[0], w01 = wp[1], w02 = wp[2];
    const float w10 = wp[3], w11 = wp[4], w12 = wp[5];
    const float w20 = wp[6], w21 = wp[7], w22 = wp[8];

    const int t = threadIdx.x;

#pragma unroll
    for (int i = 0; i < 4; ++i) {
        const int f  = t + i * 256;      // float4 index in plane [0,1024)
        const int h  = f >> 4;           // row
        const int w4 = (f & 15) << 2;    // first column of this float4

        float acx = 0.f, acy = 0.f, acz = 0.f, acw = 0.f;

#pragma unroll
        for (int kh = 0; kh < 3; ++kh) {
            const int hh = h + kh - 1;
            if (hh < 0 || hh >= H_SP) continue;   // divergent only at plane edge
            const float* __restrict__ row = xp + hh * W_SP;

            const float4 v  = *(const float4*)(row + w4);     // aligned 16B
            const float cm1 = (w4 > 0)        ? row[w4 - 1] : 0.f;
            const float c4  = (w4 < W_SP - 4) ? row[w4 + 4] : 0.f;

            float k0, k1, k2;
            if (kh == 0)      { k0 = w00; k1 = w01; k2 = w02; }
            else if (kh == 1) { k0 = w10; k1 = w11; k2 = w12; }
            else              { k0 = w20; k1 = w21; k2 = w22; }

            acx += cm1 * k0 + v.x * k1 + v.y * k2;
            acy += v.x * k0 + v.y * k1 + v.z * k2;
            acz += v.y * k0 + v.z * k1 + v.w * k2;
            acw += v.z * k0 + v.w * k1 + c4  * k2;
        }

        f32x4 acc = { acx, acy, acz, acw };
        __builtin_nontemporal_store(acc, (f32x4*)(op) + f);
    }
}

extern "C" void kernel_launch(void* const* d_in, const int* in_sizes, int n_in,
                              void* d_out, int out_size, void* d_ws, size_t ws_size,
                              hipStream_t stream) {
    const float* x = (const float*)d_in[0];
    const float* W = (const float*)d_in[1];
    float* out = (float*)d_out;

    const int n_planes = out_size / PLANE; // 8192
    dwconv3x3_direct<<<n_planes, 256, 0, stream>>>(x, W, out);
}

// Round 7
// 229.941 us; speedup vs baseline: 1.1714x; 1.1714x over previous
//
#include <hip/hip_runtime.h>

// Depthwise 3x3 conv (diagonal-masked dense conv), fp32.
// x: (S*B=32, C=256, H=64, W=64)  W: (256,256,3,3) -> only diag [c,c,:,:] used.
//
// Barrier-free wave-private-band version, VANILLA HIP ONLY (no
// global_load_lds builtin, no inline asm — rounds 5/6 suggest those may
// have killed the container):
//  - block = 1 plane, 4 waves; wave w owns output rows 16w..16w+15
//  - wave stages ITS OWN 18-row input band (incl. halo rows, redundantly;
//    2-row overlap between bands is an L2 hit) into a private LDS slice:
//    6 independent global loads issued before any consumption (the ILP the
//    round-2/4 latency-bound kernels lacked), then ds_write_b128/b32
//  - NO __syncthreads anywhere: slices are wave-private; waves drift freely
//    so the CU's VMEM queue never drains in lockstep
//  - all LDS traffic is contiguous-per-16-lane-group b128/b32 (conflict-free
//    class); horizontal halo via __shfl, NOT the 8-way-conflicted scalar
//    ds_reads of the round-0/3 kernels
//  - nontemporal float4 stores (write-once stream)

#define C_CH 256
#define H_SP 64
#define W_SP 64
#define PLANE (H_SP * W_SP)   // 4096 floats
#define BAND_ROWS 18          // 16 output rows + 2 halo rows

typedef float f32x4 __attribute__((ext_vector_type(4)));

__global__ __launch_bounds__(256) void dwconv3x3_band2(
    const float* __restrict__ x,
    const float* __restrict__ Wfull,
    float* __restrict__ out)
{
    __shared__ float lds[4 * BAND_ROWS * W_SP]; // 4 x 4608 B = 18432 B

    const int tid  = threadIdx.x;
    const int wid  = tid >> 6;          // wave = band 0..3
    const int lane = tid & 63;
    const int rr   = lane >> 4;         // row within 4-row group
    const int cc   = lane & 15;         // float4 chunk within row

    const int p  = blockIdx.x;          // plane index [0, 8192)
    const int c  = p & (C_CH - 1);      // channel
    const int r0 = wid << 4;            // first output row of this band

    const float* __restrict__ xp = x + (size_t)p * PLANE;
    float* __restrict__ op       = out + (size_t)p * PLANE;

    // 9 diagonal weights, wave-uniform: W[((c*C + c)*3 + kh)*3 + kw]
    const float* __restrict__ wp = Wfull + (size_t)c * (C_CH + 1) * 9;
    const float w00 = wp[0], w01 = wp[1], w02 = wp[2];
    const float w10 = wp[3], w11 = wp[4], w12 = wp[5];
    const float w20 = wp[6], w21 = wp[7], w22 = wp[8];

    float* tile = &lds[wid * BAND_ROWS * W_SP]; // private slice, 16B-aligned

    // ---- Stage rows r0-1 .. r0+16 (clamped) into local rows 0..17. ----
    // Local row l holds global row r0-1+l. Clamped duplicate rows (l=0 for
    // band 0, l=17 for band 3) are never read (compute skips plane edges).
    // Issue all 6 independent global loads first, then the LDS writes.
    float4 v0, v1, v2, v3;
    {
        int g0 = r0 - 1 + rr;       g0 = g0 < 0 ? 0 : g0;
        int g1 = r0 + 3 + rr;
        int g2 = r0 + 7 + rr;
        int g3 = r0 + 11 + rr;      g3 = g3 > H_SP - 1 ? H_SP - 1 : g3;
        const int co = cc << 2;
        v0 = *(const float4*)(xp + g0 * W_SP + co);
        v1 = *(const float4*)(xp + g1 * W_SP + co);
        v2 = *(const float4*)(xp + g2 * W_SP + co);
        v3 = *(const float4*)(xp + g3 * W_SP + co);
    }
    float h0, h1;
    {
        int g4 = r0 + 15;
        int g5 = r0 + 16;           g5 = g5 > H_SP - 1 ? H_SP - 1 : g5;
        h0 = xp[g4 * W_SP + lane];
        h1 = xp[g5 * W_SP + lane];
    }
    {
        const int co = cc << 2;
        *(float4*)(tile + (rr     ) * W_SP + co) = v0;   // local rows 0..3
        *(float4*)(tile + (rr +  4) * W_SP + co) = v1;   // 4..7
        *(float4*)(tile + (rr +  8) * W_SP + co) = v2;   // 8..11
        *(float4*)(tile + (rr + 12) * W_SP + co) = v3;   // 12..15
        tile[16 * W_SP + lane] = h0;                     // local row 16
        tile[17 * W_SP + lane] = h1;                     // local row 17
    }
    // No barrier: slice is wave-private; compiler's lgkmcnt ordering covers
    // the in-wave ds_write -> ds_read dependency (wave-synchronous).

    // ---- Compute: 4 output rows per lane (rows r0+4s+rr), 1 float4 each. ----
#pragma unroll
    for (int s = 0; s < 4; ++s) {
        const int h = r0 + 4 * s + rr;              // output row, always valid

        float acx = 0.f, acy = 0.f, acz = 0.f, acw = 0.f;

#pragma unroll
        for (int kh = 0; kh < 3; ++kh) {
            const int hh = h + kh - 1;
            if (hh < 0 || hh >= H_SP) continue;     // plane edge only
            const int lh = hh - r0 + 1;             // local row 0..17

            const f32x4 v = *(const f32x4*)(tile + lh * W_SP + (cc << 2));
            // halo from neighbor chunk via shuffle (conflict-free);
            // cc==0 / cc==15 are plane edges (and absorb cross-group garbage)
            float left  = __shfl_up(v.w, 1);
            float right = __shfl_down(v.x, 1);
            if (cc == 0)  left  = 0.f;
            if (cc == 15) right = 0.f;

            float k0, k1, k2;
            if (kh == 0)      { k0 = w00; k1 = w01; k2 = w02; }
            else if (kh == 1) { k0 = w10; k1 = w11; k2 = w12; }
            else              { k0 = w20; k1 = w21; k2 = w22; }

            acx += left * k0 + v.x * k1 + v.y * k2;
            acy += v.x  * k0 + v.y * k1 + v.z * k2;
            acz += v.y  * k0 + v.z * k1 + v.w * k2;
            acw += v.z  * k0 + v.w * k1 + right * k2;
        }

        f32x4 acc = { acx, acy, acz, acw };
        __builtin_nontemporal_store(acc, (f32x4*)op + (h << 4) + cc);
    }
}

extern "C" void kernel_launch(void* const* d_in, const int* in_sizes, int n_in,
                              void* d_out, int out_size, void* d_ws, size_t ws_size,
                              hipStream_t stream) {
    const float* x = (const float*)d_in[0];
    const float* W = (const float*)d_in[1];
    float* out = (float*)d_out;

    const int n_planes = out_size / PLANE; // 8192
    dwconv3x3_band2<<<n_planes, 256, 0, stream>>>(x, W, out);
}